// Round 1
// baseline (275.169 us; speedup 1.0000x reference)
//
#include <hip/hip_runtime.h>

#define B_ 8
#define L_ 2048
#define D_ 512
#define BI 64
#define BJ 64

typedef __attribute__((ext_vector_type(4))) float  floatx4;
typedef __attribute__((ext_vector_type(8))) _Float16 halfx8;
typedef __attribute__((ext_vector_type(4))) int    intx4;

static __device__ __forceinline__ unsigned short f2h_bits(float x) {
  _Float16 h = (_Float16)x;
  return __builtin_bit_cast(unsigned short, h);
}

// ---------------------------------------------------------------------------
// prep: K_f16[b][l][d] = in*kw ; Vt_f16[b][d][l] = in*vw (transposed via LDS)
// grid: (L/64, D/64, B), 256 threads
// ---------------------------------------------------------------------------
__global__ __launch_bounds__(256) void prep_kv(const float* __restrict__ in,
                                               const float* __restrict__ kw,
                                               const float* __restrict__ vw,
                                               unsigned short* __restrict__ Kh,
                                               unsigned short* __restrict__ Vt) {
  const int lt = blockIdx.x * 64;
  const int dt = blockIdx.y * 64;
  const int b  = blockIdx.z;
  const int t  = threadIdx.x;
  __shared__ unsigned short vtile[64][66];  // [l][d], +2 pad

  #pragma unroll
  for (int i = 0; i < 4; ++i) {
    int c  = i * 256 + t;          // 0..1023 float4-chunks of the 64x64 tile
    int r  = c >> 4;               // l row 0..63
    int c4 = (c & 15) * 4;         // d col 0..60
    size_t gi = ((size_t)b * L_ + (lt + r)) * D_ + (dt + c4);
    size_t wi = (size_t)(lt + r) * D_ + (dt + c4);
    float4 iv = *(const float4*)(in + gi);
    float4 kv = *(const float4*)(kw + wi);
    float4 vv = *(const float4*)(vw + wi);
    unsigned int p0 = (unsigned int)f2h_bits(iv.x * kv.x) |
                      ((unsigned int)f2h_bits(iv.y * kv.y) << 16);
    unsigned int p1 = (unsigned int)f2h_bits(iv.z * kv.z) |
                      ((unsigned int)f2h_bits(iv.w * kv.w) << 16);
    uint2 pk; pk.x = p0; pk.y = p1;
    *(uint2*)(Kh + gi) = pk;                       // 8B coalesced write
    vtile[r][c4 + 0] = f2h_bits(iv.x * vv.x);
    vtile[r][c4 + 1] = f2h_bits(iv.y * vv.y);
    vtile[r][c4 + 2] = f2h_bits(iv.z * vv.z);
    vtile[r][c4 + 3] = f2h_bits(iv.w * vv.w);
  }
  __syncthreads();
  #pragma unroll
  for (int i = 0; i < 2; ++i) {
    int c  = i * 256 + t;          // 0..511 16B-chunks of transposed tile
    int dd = c >> 3;               // d row 0..63
    int l8 = (c & 7) * 8;          // l col 0..56
    int ov[4];
    #pragma unroll
    for (int j = 0; j < 4; ++j) {
      ov[j] = (int)((unsigned int)vtile[l8 + 2 * j][dd] |
                    ((unsigned int)vtile[l8 + 2 * j + 1][dd] << 16));
    }
    intx4 o; o[0] = ov[0]; o[1] = ov[1]; o[2] = ov[2]; o[3] = ov[3];
    *(intx4*)(Vt + ((size_t)b * D_ + (dt + dd)) * L_ + (lt + l8)) = o;  // 16B
  }
}

// ---------------------------------------------------------------------------
// flash attention: grid (L/BI, B), 256 threads = 4 waves, wave w owns i-strip w
// ---------------------------------------------------------------------------
__global__ __launch_bounds__(256, 1) void flash(const float* __restrict__ in,
                                                const float* __restrict__ qw,
                                                const unsigned short* __restrict__ Kh,
                                                const unsigned short* __restrict__ Vt,
                                                float* __restrict__ out) {
  const int b    = blockIdx.y;
  const int i0   = blockIdx.x * BI;
  const int tid  = threadIdx.x;
  const int w    = tid >> 6;
  const int lane = tid & 63;
  const int ln16 = lane & 15;
  const int quad = lane >> 4;

  __shared__ unsigned short Ksh[BJ][520];   // [j][d] +8 pad  (66.5 KB)
  __shared__ unsigned short Vsh[D_][72];    // [d][j] +8 pad  (73.7 KB)
  __shared__ unsigned short Psh[BI][72];    // [i][j] +8 pad  ( 9.2 KB)

  const float kScale = 0.51012599f;  // log2(e)/sqrt(8), exp2-domain softmax

  // ---- Q fragments in registers (A-layout: m=ln16, k=quad*8+t) ----
  halfx8 qf[16];
  {
    const int qi = i0 + w * 16 + ln16;
    const float* ip = in + ((size_t)b * L_ + qi) * D_;
    const float* wp = qw + (size_t)qi * D_;
    #pragma unroll
    for (int ks = 0; ks < 16; ++ks) {
      int d0 = ks * 32 + quad * 8;
      float4 a0 = *(const float4*)(ip + d0);
      float4 a1 = *(const float4*)(ip + d0 + 4);
      float4 w0 = *(const float4*)(wp + d0);
      float4 w1 = *(const float4*)(wp + d0 + 4);
      halfx8 q;
      q[0] = (_Float16)(a0.x * w0.x * kScale);
      q[1] = (_Float16)(a0.y * w0.y * kScale);
      q[2] = (_Float16)(a0.z * w0.z * kScale);
      q[3] = (_Float16)(a0.w * w0.w * kScale);
      q[4] = (_Float16)(a1.x * w1.x * kScale);
      q[5] = (_Float16)(a1.y * w1.y * kScale);
      q[6] = (_Float16)(a1.z * w1.z * kScale);
      q[7] = (_Float16)(a1.w * w1.w * kScale);
      qf[ks] = q;
    }
  }

  float m_r[4], l_r[4];
  #pragma unroll
  for (int r = 0; r < 4; ++r) { m_r[r] = -1e30f; l_r[r] = 0.f; }
  floatx4 O[32];
  #pragma unroll
  for (int ct = 0; ct < 32; ++ct) O[ct] = (floatx4){0.f, 0.f, 0.f, 0.f};

  for (int jb = 0; jb < L_ / BJ; ++jb) {
    const int j0 = jb * BJ;
    // ---- stage K tile (64 rows x 1KB) ----
    const unsigned short* kp = Kh + ((size_t)b * L_ + j0) * D_;
    #pragma unroll
    for (int i = 0; i < 16; ++i) {
      int c = i * 256 + tid;
      int r = c >> 6, c16 = c & 63;
      intx4 v = *(const intx4*)(kp + (size_t)r * D_ + c16 * 8);
      *(intx4*)(&Ksh[r][c16 * 8]) = v;
    }
    // ---- stage Vt tile (512 rows x 128B) ----
    const unsigned short* vp = Vt + (size_t)b * D_ * L_ + j0;
    #pragma unroll
    for (int i = 0; i < 16; ++i) {
      int c = i * 256 + tid;
      int r = c >> 3, c8 = c & 7;
      intx4 v = *(const intx4*)(vp + (size_t)r * L_ + c8 * 8);
      *(intx4*)(&Vsh[r][c8 * 8]) = v;
    }
    __syncthreads();

    // ---- S = Q K^T  (exp2-domain logits) ----
    floatx4 s[4];
    #pragma unroll
    for (int jt = 0; jt < 4; ++jt) {
      floatx4 acc = {0.f, 0.f, 0.f, 0.f};
      #pragma unroll
      for (int ks = 0; ks < 16; ++ks) {
        halfx8 bk = *(const halfx8*)(&Ksh[jt * 16 + ln16][ks * 32 + quad * 8]);
        acc = __builtin_amdgcn_mfma_f32_16x16x32_f16(qf[ks], bk, acc, 0, 0, 0);
      }
      s[jt] = acc;
    }

    // ---- online softmax (rows = quad*4 + r of this wave's strip) ----
    float mt[4];
    #pragma unroll
    for (int r = 0; r < 4; ++r)
      mt[r] = fmaxf(fmaxf(s[0][r], s[1][r]), fmaxf(s[2][r], s[3][r]));
    #pragma unroll
    for (int off = 1; off < 16; off <<= 1) {
      #pragma unroll
      for (int r = 0; r < 4; ++r)
        mt[r] = fmaxf(mt[r], __shfl_xor(mt[r], off));
    }
    float al[4], ts[4];
    bool upd = false;
    #pragma unroll
    for (int r = 0; r < 4; ++r) {
      float mn = fmaxf(m_r[r], mt[r]);
      al[r] = exp2f(m_r[r] - mn);
      upd = upd || (mn != m_r[r]);
      m_r[r] = mn;
      ts[r] = 0.f;
      #pragma unroll
      for (int jt = 0; jt < 4; ++jt) {
        s[jt][r] = exp2f(s[jt][r] - mn);
        ts[r] += s[jt][r];
      }
    }
    #pragma unroll
    for (int off = 1; off < 16; off <<= 1) {
      #pragma unroll
      for (int r = 0; r < 4; ++r)
        ts[r] += __shfl_xor(ts[r], off);
    }
    #pragma unroll
    for (int r = 0; r < 4; ++r) l_r[r] = l_r[r] * al[r] + ts[r];

    if (__any((int)upd)) {
      #pragma unroll
      for (int ct = 0; ct < 32; ++ct) {
        #pragma unroll
        for (int r = 0; r < 4; ++r) O[ct][r] *= al[r];
      }
    }

    // ---- P: C-layout regs -> A-layout via LDS (same-wave, no barrier) ----
    #pragma unroll
    for (int jt = 0; jt < 4; ++jt) {
      #pragma unroll
      for (int r = 0; r < 4; ++r)
        Psh[w * 16 + quad * 4 + r][jt * 16 + ln16] = f2h_bits(s[jt][r]);
    }
    halfx8 pf[2];
    #pragma unroll
    for (int kc = 0; kc < 2; ++kc)
      pf[kc] = *(const halfx8*)(&Psh[w * 16 + ln16][kc * 32 + quad * 8]);

    // ---- O += P V ----
    #pragma unroll
    for (int ct = 0; ct < 32; ++ct) {
      #pragma unroll
      for (int kc = 0; kc < 2; ++kc) {
        halfx8 vf = *(const halfx8*)(&Vsh[ct * 16 + ln16][kc * 32 + quad * 8]);
        O[ct] = __builtin_amdgcn_mfma_f32_16x16x32_f16(pf[kc], vf, O[ct], 0, 0, 0);
      }
    }
    __syncthreads();
  }

  // ---- epilogue: O / l ----
  float inv[4];
  #pragma unroll
  for (int r = 0; r < 4; ++r) inv[r] = 1.0f / l_r[r];
  float* op = out + ((size_t)b * L_ + i0 + w * 16 + quad * 4) * D_ + ln16;
  #pragma unroll
  for (int r = 0; r < 4; ++r) {
    #pragma unroll
    for (int ct = 0; ct < 32; ++ct)
      op[(size_t)r * D_ + ct * 16] = O[ct][r] * inv[r];
  }
}

// ---------------------------------------------------------------------------
extern "C" void kernel_launch(void* const* d_in, const int* in_sizes, int n_in,
                              void* d_out, int out_size, void* d_ws, size_t ws_size,
                              hipStream_t stream) {
  const float* in = (const float*)d_in[0];
  const float* qw = (const float*)d_in[1];
  const float* kw = (const float*)d_in[2];
  const float* vw = (const float*)d_in[3];
  float* out = (float*)d_out;

  unsigned short* Kh = (unsigned short*)d_ws;                 // 16.78 MB
  unsigned short* Vt = Kh + (size_t)B_ * L_ * D_;             // 16.78 MB

  dim3 gp(L_ / 64, D_ / 64, B_);
  prep_kv<<<gp, dim3(256), 0, stream>>>(in, kw, vw, Kh, Vt);
  dim3 gf(L_ / BI, B_);
  flash<<<gf, dim3(256), 0, stream>>>(in, qw, Kh, Vt, out);
}